// Round 1
// 360.478 us; speedup vs baseline: 1.0069x; 1.0069x over previous
//
#include <hip/hip_runtime.h>

#define V 128
#define D 20
#define NUM_EMB (V * V * V)

typedef float v4f __attribute__((ext_vector_type(4)));

// 5 threads per point: thread (i, k) computes float4 chunk k (floats 4k..4k+3)
// of output row i. Each thread issues 8 independent 16B gathers (one per
// corner). sched_barrier(0) between the issue loop and the use loop forces
// all 8 loads to be in flight simultaneously (without it the compiler
// re-associates into load->wait->FMA with ~28 VGPRs and ~3-deep MLP).
__global__ __launch_bounds__(320) void dense_grid_enc_kernel(
    const float* __restrict__ x, const float* __restrict__ grid,
    float* __restrict__ out, int N)
{
    int tid = threadIdx.x;            // 0..319
    int lp  = tid / 5;                // local point 0..63
    int k   = tid - lp * 5;           // chunk 0..4
    int i   = blockIdx.x * 64 + lp;   // global point
    if (i >= N) return;

    float px = x[3 * i + 0];
    float py = x[3 * i + 1];
    float pz = x[3 * i + 2];

    // gp = floor((p+1)*64); cell spacing is exactly 1/64 in fp32
    int ix = (int)floorf((px + 1.0f) * 64.0f);
    int iy = (int)floorf((py + 1.0f) * 64.0f);
    int iz = (int)floorf((pz + 1.0f) * 64.0f);

    int f000 = ix + iy * V + iz * V * V;

    // Per-corner flat indices, clamped like the JAX gather (OOB clip).
    int flats[8];
    flats[0] = f000;
    flats[1] = f000 + 1;
    flats[2] = f000 + V;
    flats[3] = f000 + V + 1;
    flats[4] = f000 + V * V;
    flats[5] = f000 + V * V + 1;
    flats[6] = f000 + V * V + V;
    flats[7] = f000 + V * V + V + 1;
    #pragma unroll
    for (int c = 0; c < 8; c++) {
        if (flats[c] > NUM_EMB - 1) flats[c] = NUM_EMB - 1;
    }

    // 32-bit byte offsets from the uniform grid base: saddr + voffset form,
    // no per-lane 64-bit address pairs. max = (NUM_EMB-1)*80 + 64 < 2^28.
    const char* gbase = (const char*)grid;
    unsigned koff = (unsigned)(16 * k);

    // Issue all 8 independent 16B gathers before any use.
    v4f q[8];
    #pragma unroll
    for (int c = 0; c < 8; c++) {
        unsigned off = (unsigned)flats[c] * 80u + koff;
        q[c] = *(const v4f*)(gbase + (size_t)off);
    }

    // Weight computation overlaps the gather latency (VALU is ~92% idle).
    float x1 = (float)ix * (2.0f / 128.0f) - 1.0f;
    float y1 = (float)iy * (2.0f / 128.0f) - 1.0f;
    float z1 = (float)iz * (2.0f / 128.0f) - 1.0f;
    float x2 = x1 + (2.0f / 128.0f);
    float y2 = y1 + (2.0f / 128.0f);
    float z2 = z1 + (2.0f / 128.0f);

    float wx[2], wy[2], wz[2];
    wx[1] = (px - x1) * 64.0f; wx[0] = (x2 - px) * 64.0f;
    wy[1] = (py - y1) * 64.0f; wy[0] = (y2 - py) * 64.0f;
    wz[1] = (pz - z1) * 64.0f; wz[0] = (z2 - pz) * 64.0f;

    // Nothing schedules across this: all 8 loads stay issued above, all
    // consumption stays below -> 8-deep MLP per wave is forced.
    __builtin_amdgcn_sched_barrier(0);

    // Recompute each corner weight from the 6 base weights (saves 8 VGPRs
    // vs a w[8] array; keeps total allocation under the 64-VGPR cliff).
    v4f acc = (v4f)(0.0f);
    #pragma unroll
    for (int c = 0; c < 8; c++) {
        float w = wx[c & 1] * wy[(c >> 1) & 1] * wz[(c >> 2) & 1];
        acc += w * q[c];
    }

    // out row i, chunk k: block-wide stores are one contiguous 5KB span
    __builtin_nontemporal_store(acc, (v4f*)(out + (size_t)i * D + 4 * k));
}

extern "C" void kernel_launch(void* const* d_in, const int* in_sizes, int n_in,
                              void* d_out, int out_size, void* d_ws, size_t ws_size,
                              hipStream_t stream) {
    const float* x = (const float*)d_in[0];
    const float* grid = (const float*)d_in[1];
    float* out = (float*)d_out;
    int N = in_sizes[0] / 3;

    int pts_per_block = 64;
    int nblocks = (N + pts_per_block - 1) / pts_per_block;
    dense_grid_enc_kernel<<<nblocks, 320, 0, stream>>>(x, grid, out, N);
}